// Round 9
// baseline (240.654 us; speedup 1.0000x reference)
//
#include <hip/hip_runtime.h>
#include <hip/hip_bf16.h>

// x (16,512,512,3) fp32 NHWC -> out (16,3,512,512,3):
//   out[b][s][h][w][c] = avgpool_same_{k_s}(x) - x,  k in {7,15,31},
// exclude-padding averages (count = rowcnt(h)*colcnt(w)).
//
// K1 (fused): row prefix + 16-row-block vertical prefix + block totals T.
// K2: 8-wide threads; window = I[rt] - I[rb-1] + T fixups; x derived from I;
//     XCD-banded h mapping for L2 reuse; nontemporal out stores.

#define HH 512
#define WW 512
#define ROWF 1536               // data floats per row (512*3)
#define NROWS (16 * HH)
#define PADL 48                 // 16 px * 3 c
#define PADR 48
#define RSTR (PADL + ROWF + PADR)  // 1632 floats
#define HBLK 16
#define NBLK (HH / HBLK)        // 32
#define NB 16
#define RPW (HBLK / 4)          // rows per wave = 4

typedef float nfloat4 __attribute__((ext_vector_type(4)));  // native vec for nt-store

static const size_t I_FLOATS = (size_t)NB * HH * RSTR;     // 13,369,344
static const size_t T_FLOATS = (size_t)NB * NBLK * RSTR;   // 835,584

// ---------------- K1: fused row prefix + vertical partial prefix --------
__global__ __launch_bounds__(256) void fused_prefix(
    const float* __restrict__ x, float* __restrict__ I, float* __restrict__ T) {
  __shared__ float wtot[4][64][25];   // stride 25 -> bank-conflict-free
  const int wv = threadIdx.x >> 6;
  const int lane = threadIdx.x & 63;
  const int blk = blockIdx.x;         // 0..NBLK-1
  const int b = blockIdx.y;           // 0..NB-1
  const int row0 = b * HH + blk * HBLK + wv * RPW;

  float acc[24];
#pragma unroll
  for (int j = 0; j < 24; ++j) acc[j] = 0.f;

  for (int rr = 0; rr < RPW; ++rr) {
    const int row = row0 + rr;
    const float4* s4 = (const float4*)(x + (size_t)row * ROWF + lane * 24);
    float v[24];
#pragma unroll
    for (int i = 0; i < 6; ++i) {
      float4 t = s4[i];
      v[4*i] = t.x; v[4*i+1] = t.y; v[4*i+2] = t.z; v[4*i+3] = t.w;
    }
    float tot[3];
#pragma unroll
    for (int c = 0; c < 3; ++c) {
      float run = 0.f;
#pragma unroll
      for (int wl = 0; wl < 8; ++wl) { run += v[wl*3+c]; v[wl*3+c] = run; }
      tot[c] = run;
    }
#pragma unroll
    for (int c = 0; c < 3; ++c) {
      float t = tot[c];
#pragma unroll
      for (int d = 1; d < 64; d <<= 1) {
        float n = __shfl_up(t, d, 64);
        if (lane >= d) t += n;
      }
      float off = t - tot[c];
#pragma unroll
      for (int wl = 0; wl < 8; ++wl) v[wl*3+c] += off;
    }
#pragma unroll
    for (int j = 0; j < 24; ++j) acc[j] += v[j];

    float rp0 = __shfl(acc[21], 63, 64);
    float rp1 = __shfl(acc[22], 63, 64);
    float rp2 = __shfl(acc[23], 63, 64);

    float* dst = I + (size_t)row * RSTR;
    float4* d4 = (float4*)(dst + PADL + lane * 24);
#pragma unroll
    for (int i = 0; i < 6; ++i)
      d4[i] = make_float4(acc[4*i], acc[4*i+1], acc[4*i+2], acc[4*i+3]);
    if (lane < 12) {
      ((float4*)dst)[lane] = make_float4(0.f, 0.f, 0.f, 0.f);
      float rp[3] = {rp0, rp1, rp2};
      float p[4];
#pragma unroll
      for (int j = 0; j < 4; ++j) p[j] = rp[(lane * 4 + j) % 3];
      ((float4*)(dst + PADL + ROWF))[lane] = make_float4(p[0], p[1], p[2], p[3]);
    }
  }

#pragma unroll
  for (int j = 0; j < 24; ++j) wtot[wv][lane][j] = acc[j];
  __syncthreads();

  if (wv == 0) {
    float tt[24];
#pragma unroll
    for (int j = 0; j < 24; ++j)
      tt[j] = wtot[0][lane][j] + wtot[1][lane][j] + wtot[2][lane][j] + wtot[3][lane][j];
    float* trow = T + ((size_t)b * NBLK + blk) * RSTR;
    float4* t4 = (float4*)(trow + PADL + lane * 24);
#pragma unroll
    for (int i = 0; i < 6; ++i)
      t4[i] = make_float4(tt[4*i], tt[4*i+1], tt[4*i+2], tt[4*i+3]);
    if (lane < 12) {
      ((float4*)trow)[lane] = make_float4(0.f, 0.f, 0.f, 0.f);
      float tp[3];
#pragma unroll
      for (int c = 0; c < 3; ++c)
        tp[c] = wtot[0][63][21+c] + wtot[1][63][21+c] +
                wtot[2][63][21+c] + wtot[3][63][21+c];
      float p[4];
#pragma unroll
      for (int j = 0; j < 4; ++j) p[j] = tp[(lane * 4 + j) % 3];
      ((float4*)(trow + PADL + ROWF))[lane] = make_float4(p[0], p[1], p[2], p[3]);
    }
  } else {
    float off[24];
#pragma unroll
    for (int j = 0; j < 24; ++j) {
      float o = wtot[0][lane][j];
      if (wv >= 2) o += wtot[1][lane][j];
      if (wv >= 3) o += wtot[2][lane][j];
      off[j] = o;
    }
    float offp[3];
#pragma unroll
    for (int c = 0; c < 3; ++c) {
      float o = wtot[0][63][21+c];
      if (wv >= 2) o += wtot[1][63][21+c];
      if (wv >= 3) o += wtot[2][63][21+c];
      offp[c] = o;
    }
    for (int rr = 0; rr < RPW; ++rr) {
      float* dst = I + (size_t)(row0 + rr) * RSTR;
      float4* d4 = (float4*)(dst + PADL + lane * 24);
#pragma unroll
      for (int i = 0; i < 6; ++i) {
        float4 t = d4[i];
        t.x += off[4*i]; t.y += off[4*i+1]; t.z += off[4*i+2]; t.w += off[4*i+3];
        d4[i] = t;
      }
      if (lane < 12) {
        float4* rp = ((float4*)(dst + PADL + ROWF)) + lane;
        float4 t = *rp;
        t.x += offp[(lane*4+0)%3]; t.y += offp[(lane*4+1)%3];
        t.z += offp[(lane*4+2)%3]; t.w += offp[(lane*4+3)%3];
        *rp = t;
      }
    }
  }
}

// ---------------- K2: per-(b,h) window deviations, 8 floats/thread ------
// hi[j] = Rp[r3+j]   (floats r3-1 .. r3+10 : 3 aligned float4)
// lo[j] = Rp[j-r3-3] (floats -r3-3 .. -r3+4: 2 aligned float4)
template <bool SUB>
__device__ __forceinline__ void acc_hsum8(const float* __restrict__ Rp,
                                          int r3, float* hs) {
  float4 A = *(const float4*)(Rp + r3 - 1);
  float4 B = *(const float4*)(Rp + r3 + 3);
  float4 C = *(const float4*)(Rp + r3 + 7);
  float4 D = *(const float4*)(Rp - r3 - 3);
  float4 E = *(const float4*)(Rp - r3 + 1);
  float hi[8] = {A.y, A.z, A.w, B.x, B.y, B.z, B.w, C.x};
  float lo[8] = {D.x, D.y, D.z, D.w, E.x, E.y, E.z, E.w};
#pragma unroll
  for (int j = 0; j < 8; ++j) {
    float d = hi[j] - lo[j];
    hs[j] = SUB ? hs[j] - d : hs[j] + d;
  }
}

__global__ __launch_bounds__(384) void win_dev_ii(
    const float* __restrict__ I, const float* __restrict__ T,
    float* __restrict__ out) {
  const int bx = blockIdx.x;          // 0..255 (row pairs)
  // XCD band swizzle: each XCD owns a contiguous 64-row band.
  const int hp = ((bx & 7) << 5) + (bx >> 3);
  const int ty = (threadIdx.x >= 192) ? 1 : 0;   // waves 0-2: row0, 3-5: row1
  const int h = hp * 2 + ty;
  const int b = blockIdx.y;
  const int f = (threadIdx.x - ty * 192) * 8;    // 0..1528
  const float* Ib = I + (size_t)b * HH * RSTR;
  const float* Tb = T + (size_t)b * NBLK * RSTR;
  float* ob = out + ((size_t)b * 3 * HH + h) * ROWF + f;

  // derive x[h][f..f+7] from I: x = dW(I[h]) - dW(I[h-1]), dW(R)[j]=R[j]-R[j-3]
  const float* Rh = Ib + (size_t)h * RSTR + PADL + f;
  float xs[8];
  {
    float4 P0 = *(const float4*)(Rh - 4);
    float4 Q0 = *(const float4*)(Rh);
    float4 R0 = *(const float4*)(Rh + 4);
    float ar[12] = {P0.x,P0.y,P0.z,P0.w, Q0.x,Q0.y,Q0.z,Q0.w, R0.x,R0.y,R0.z,R0.w};
#pragma unroll
    for (int j = 0; j < 8; ++j) xs[j] = ar[j+4] - ar[j+1];
    if (h & (HBLK - 1)) {             // h-1 in same vertical block
      const float* Rm = Rh - RSTR;
      float4 P1 = *(const float4*)(Rm - 4);
      float4 Q1 = *(const float4*)(Rm);
      float4 R1 = *(const float4*)(Rm + 4);
      float am[12] = {P1.x,P1.y,P1.z,P1.w, Q1.x,Q1.y,Q1.z,Q1.w, R1.x,R1.y,R1.z,R1.w};
#pragma unroll
      for (int j = 0; j < 8; ++j) xs[j] -= am[j+4] - am[j+1];
    }
  }

  const int RADv[3] = {3, 7, 15};
#pragma unroll
  for (int s = 0; s < 3; ++s) {
    const int r = RADv[s], r3 = 3 * r;
    const int rt = min(h + r, HH - 1);
    const int rb = h - r;
    float hs[8];
#pragma unroll
    for (int j = 0; j < 8; ++j) hs[j] = 0.f;
    acc_hsum8<false>(Ib + (size_t)rt * RSTR + PADL + f, r3, hs);
    const int bt = rt >> 4;
    if (rb >= 1) {
      acc_hsum8<true>(Ib + (size_t)(rb - 1) * RSTR + PADL + f, r3, hs);
      for (int k = (rb - 1) >> 4; k < bt; ++k)      // <=2 iters (HBLK=16)
        acc_hsum8<false>(Tb + (size_t)k * RSTR + PADL + f, r3, hs);
    } else {
      for (int k = 0; k < bt; ++k)                  // <=1 iter
        acc_hsum8<false>(Tb + (size_t)k * RSTR + PADL + f, r3, hs);
    }
    const int rowcnt = rt - max(rb, 0) + 1;
    const float invrow = __builtin_amdgcn_rcpf((float)rowcnt);
    float rv[8];
#pragma unroll
    for (int j = 0; j < 8; ++j) {
      const int wj = (f + j) / 3;
      const int cc = min(wj + r, WW - 1) - max(wj - r, 0) + 1;
      rv[j] = hs[j] * (invrow * __builtin_amdgcn_rcpf((float)cc)) - xs[j];
    }
    // out is write-once: bypass L2 so I rows stay resident
    float* op = ob + (size_t)s * HH * ROWF;
    nfloat4 s0; s0.x = rv[0]; s0.y = rv[1]; s0.z = rv[2]; s0.w = rv[3];
    nfloat4 s1; s1.x = rv[4]; s1.y = rv[5]; s1.z = rv[6]; s1.w = rv[7];
    __builtin_nontemporal_store(s0, (nfloat4*)op);
    __builtin_nontemporal_store(s1, (nfloat4*)(op + 4));
  }
}

// ================= fallback path (round-3, proven passing) ==============
__global__ __launch_bounds__(256) void row_prefix_kernel(
    const float* __restrict__ x, float* __restrict__ P) {
  const int wave = threadIdx.x >> 6;
  const int lane = threadIdx.x & 63;
  const int row = blockIdx.x * 4 + wave;
  const size_t base = (size_t)row * ROWF + (size_t)lane * 24;
  float v[24];
  const float4* s4 = reinterpret_cast<const float4*>(x + base);
#pragma unroll
  for (int i = 0; i < 6; ++i) {
    float4 t = s4[i];
    v[i*4] = t.x; v[i*4+1] = t.y; v[i*4+2] = t.z; v[i*4+3] = t.w;
  }
  float tot[3];
#pragma unroll
  for (int c = 0; c < 3; ++c) {
    float run = 0.f;
#pragma unroll
    for (int wl = 0; wl < 8; ++wl) { run += v[wl*3+c]; v[wl*3+c] = run; }
    tot[c] = run;
  }
#pragma unroll
  for (int c = 0; c < 3; ++c) {
    float t = tot[c];
#pragma unroll
    for (int d = 1; d < 64; d <<= 1) {
      float n = __shfl_up(t, d, 64);
      if (lane >= d) t += n;
    }
    float off = t - tot[c];
#pragma unroll
    for (int wl = 0; wl < 8; ++wl) v[wl*3+c] += off;
  }
  float4* d4 = reinterpret_cast<float4*>(P + base);
#pragma unroll
  for (int i = 0; i < 6; ++i)
    d4[i] = make_float4(v[i*4], v[i*4+1], v[i*4+2], v[i*4+3]);
}

__global__ __launch_bounds__(256) void window_dev_kernel(
    const float* __restrict__ x, const float* __restrict__ P,
    float* __restrict__ out) {
  const int RAD[3] = {3, 7, 15};
  const int flat = blockIdx.x * 256 + threadIdx.x;
  const int w = flat / 3;
  const int c = flat - w * 3;
  const int b = blockIdx.z;
  const int h0 = blockIdx.y * 64;
  const float* Pb = P + (size_t)b * HH * ROWF;
  const float* xb = x + (size_t)b * HH * ROWF;
  float* ob = out + (size_t)b * 3 * HH * ROWF;
  int ihi[3], ilo[3];
  float mlo[3], invcol[3];
#pragma unroll
  for (int s = 0; s < 3; ++s) {
    const int r = RAD[s];
    int lo = w - r; if (lo < 0) lo = 0;
    int hi = w + r; if (hi > WW - 1) hi = WW - 1;
    invcol[s] = __builtin_amdgcn_rcpf((float)(hi - lo + 1));
    ihi[s] = hi * 3 + c;
    ilo[s] = (lo > 0) ? ((lo - 1) * 3 + c) : c;
    mlo[s] = (lo > 0) ? 1.f : 0.f;
  }
  float S[3];
#pragma unroll
  for (int s = 0; s < 3; ++s) {
    const int r = RAD[s];
    int r0 = h0 - r; if (r0 < 0) r0 = 0;
    int r1 = h0 + r; if (r1 > HH - 1) r1 = HH - 1;
    float acc = 0.f;
    for (int hh = r0; hh <= r1; ++hh) {
      const float* Pr = Pb + (size_t)hh * ROWF;
      acc += Pr[ihi[s]] - mlo[s] * Pr[ilo[s]];
    }
    S[s] = acc;
  }
  for (int h = h0; h < h0 + 64; ++h) {
    const float xvv = xb[(size_t)h * ROWF + flat];
    float invrow[3];
#pragma unroll
    for (int s = 0; s < 3; ++s) {
      const int r = RAD[s];
      int rt = h + r; if (rt > HH - 1) rt = HH - 1;
      int rbv = h - r; if (rbv < 0) rbv = 0;
      invrow[s] = __builtin_amdgcn_rcpf((float)(rt - rbv + 1));
    }
#pragma unroll
    for (int s = 0; s < 3; ++s) {
      const int r = RAD[s];
      const float avg = S[s] * (invrow[s] * invcol[s]);
      ob[((size_t)s * HH + h) * ROWF + flat] = avg - xvv;
      const int add = h + 1 + r;
      const int rem = h - r;
      float d = 0.f;
      if (add < HH) {
        const float* Pr = Pb + (size_t)add * ROWF;
        d += Pr[ihi[s]] - mlo[s] * Pr[ilo[s]];
      }
      if (rem >= 0) {
        const float* Pr = Pb + (size_t)rem * ROWF;
        d -= Pr[ihi[s]] - mlo[s] * Pr[ilo[s]];
      }
      S[s] += d;
    }
  }
}

// ========================================================================
extern "C" void kernel_launch(void* const* d_in, const int* in_sizes, int n_in,
                              void* d_out, int out_size, void* d_ws, size_t ws_size,
                              hipStream_t stream) {
  const float* x = (const float*)d_in[0];
  float* outp = (float*)d_out;
  const size_t need = (I_FLOATS + T_FLOATS) * sizeof(float);

  if (ws_size >= need) {
    float* I = (float*)d_ws;
    float* T = I + I_FLOATS;
    dim3 g1(NBLK, NB);                 // (32,16): 512 blocks x 4 waves
    fused_prefix<<<g1, 256, 0, stream>>>(x, I, T);
    dim3 g2(HH / 2, NB);               // (256,16): 2 rows per block
    win_dev_ii<<<g2, 384, 0, stream>>>(I, T, outp);
  } else {
    float* P = (float*)d_ws;
    row_prefix_kernel<<<NROWS / 4, 256, 0, stream>>>(x, P);
    dim3 grid(ROWF / 256, HH / 64, 16);
    window_dev_kernel<<<grid, 256, 0, stream>>>(x, P, outp);
  }
}